// Round 6
// baseline (266.457 us; speedup 1.0000x reference)
//
#include <hip/hip_runtime.h>
#include <hip/hip_fp16.h>

// AudioStructuralAnalyzer fused kernel, round 8.
// vs round 7 (132 us, VALUBusy 46%, Occupancy 40% -> LDS-latency bound at
// ~3 waves/SIMD):
//  - SAME 32x32 tile, SAME LDS (32.6 KB), SAME math — but 512-thread blocks
//    (32x16, 8 waves). 4 blocks/CU x 8 waves = 32 waves/CU cap (was 20).
//    Grid-stride trip counts halve; per-slot duration halves; ~2x waves per
//    SIMD to hide ~120cy ds_read latency inside each barrier slot.
//  - acc[6][4] -> acc[6][2] (each thread owns 2 output rows, ty+16s).
//  - __launch_bounds__(512, 8): 8 waves/EU min -> VGPR capped at 64 (the
//    256-thread build already fit 64 with more live state).
// Arithmetic bit-identical to rounds 4/7 (absmax stays 0.00390625).

#define F_DIM 256
#define T_DIM 2048
#define B_DIM 8
#define C_DIM 2
#define TILE  32
#define NTHR  512

#define XROWS 40          // x tile: halo 4
#define XS    40          // even stride (float2 loads stay aligned)
#define UROWS 38          // (ux,uy): halo 3
#define US    40          // stored with +1 col shift: u(r,cc) at word r*US+cc+1
#define FROWS 36          // field tiles: halo 2
#define FS    36
#define FH2   18          // FS/2 uint2 pairs per row
#define EPSF  1e-10f

template<bool V> struct BoolC { static constexpr bool value = V; };

static __device__ __forceinline__ __half2 pack_h2(float a, float b) {
    auto v = __builtin_amdgcn_cvt_pkrtz(a, b);   // v_cvt_pkrtz_f16_f32, 1 inst
    return *(__half2*)&v;
}
static __device__ __forceinline__ float clamp01(float x) {
    return fminf(fmaxf(x, 0.f), 1.f);
}

__global__ __launch_bounds__(512, 8)
void audio_struct_fused(const float* __restrict__ x_in,
                        const float* __restrict__ gk_in,
                        float* __restrict__ out)
{
    __shared__ __align__(16) float   s_x [XROWS*XS];    // 6400 B
    __shared__ __align__(16) __half2 s_u [UROWS*US];    // 6080 B (ux,uy), col-shifted
    __shared__ __align__(16) __half2 s_P0[FROWS*FS];    // 5184 B (trace,diff)
    __shared__ __align__(16) __half2 s_P1[FROWS*FS];    // 5184 B (sxy,tin) -> (ua,va)
    __shared__ __align__(16) __half2 s_P2[FROWS*FS];    // 5184 B (sf,cv)
    __shared__ __align__(16) float   s_tmp[TILE*FS];    // 4608 B ping-pong
    // total 32640 B -> 4 blocks/CU x 8 waves = 32 waves/CU cap

    const int tx  = threadIdx.x;          // 0..31 (time)
    const int ty  = threadIdx.y;          // 0..15 (freq)
    const int tid = ty * 32 + tx;         // 0..511
    const int t0  = blockIdx.x * TILE;
    const int f0  = blockIdx.y * TILE;
    const int b   = blockIdx.z;

    // 1D gaussian = normalized middle row of the separable 5x5 kernel
    float r0 = gk_in[10], r1 = gk_in[11], r2 = gk_in[12], r3 = gk_in[13], r4 = gk_in[14];
    float winv = __builtin_amdgcn_rcpf(r0 + r1 + r2 + r3 + r4);
    const float w[5] = {r0*winv, r1*winv, r2*winv, r3*winv, r4*winv};
    const __half2 wh2[5] = {pack_h2(w[0],w[0]), pack_h2(w[1],w[1]), pack_h2(w[2],w[2]),
                            pack_h2(w[3],w[3]), pack_h2(w[4],w[4])};
    const __half2 h2z    = pack_h2(0.f, 0.f);
    const __half2 two    = pack_h2(2.f, 2.f);
    const __half2 eighth = pack_h2(0.125f, 0.125f);

    // paired pk vertical pass: dst[idx] = sum_i w[i]*src[idx + i*FH2] (uint2 lanes)
    auto vpass_pair = [&](const __half2* src, __half2* dst) {
        const uint2* s = (const uint2*)src;
        uint2* d = (uint2*)dst;
        for (int idx = tid; idx < TILE * FH2; idx += NTHR) {
            __half2 a0 = h2z, a1 = h2z;
            #pragma unroll
            for (int i = 0; i < 5; ++i) {
                uint2 v = s[idx + i * FH2];
                a0 = __hfma2(wh2[i], *(const __half2*)&v.x, a0);
                a1 = __hfma2(wh2[i], *(const __half2*)&v.y, a1);
            }
            uint2 o; o.x = *(const unsigned*)&a0; o.y = *(const unsigned*)&a1;
            d[idx] = o;
        }
    };

    float acc[6][2];
    #pragma unroll
    for (int k = 0; k < 6; ++k)
        #pragma unroll
        for (int s = 0; s < 2; ++s) acc[k][s] = 0.0f;

    const bool interior = (f0 >= 4) && (f0 + TILE + 4 <= F_DIM) &&
                          (t0 >= 4) && (t0 + TILE + 4 <= T_DIM);

    // ---- Phases A, B, C(+D1) templated on interior fast path ----
    auto phaseABCD1 = [&](const float* xp, auto FASTC) {
        constexpr bool FAST = decltype(FASTC)::value;

        // ---- Phase A: load x tile + halo 4 (float2, never straddles edges) ----
        for (int idx = tid; idx < XROWS * 20; idx += NTHR) {
            int r  = idx / 20, c2 = idx - r * 20;
            float2 v;
            if (FAST) {
                v = *(const float2*)(xp + (size_t)(f0 + r - 4) * T_DIM + (t0 + c2 * 2 - 4));
            } else {
                int gf = f0 + r - 4;
                int gt = t0 + c2 * 2 - 4;
                v = make_float2(0.f, 0.f);
                if ((unsigned)gf < (unsigned)F_DIM && (unsigned)gt < (unsigned)T_DIM)
                    v = *(const float2*)(xp + (size_t)gf * T_DIM + gt);
            }
            *(float2*)&s_x[r * XS + c2 * 2] = v;
        }
        __syncthreads();

        // ---- Phase B: (ux,uy) on 38x38; packed fields on 36x36 ----
        for (int idx = tid; idx < UROWS * UROWS; idx += NTHR) {
            int r = idx / UROWS, cc = idx - r * UROWS;
            float ux = 0.f, uy = 0.f, trp = 0.f, dfp = 0.f, sxy = 0.f,
                  tin = 0.f, sf = 0.f;
            bool ok = true;
            if (!FAST) {
                int gfr = f0 + r - 3, gtc = t0 + cc - 3;
                ok = ((unsigned)gfr < (unsigned)F_DIM) & ((unsigned)gtc < (unsigned)T_DIM);
            }
            if (ok) {
                const float* xc = &s_x[(r + 1) * XS + (cc + 1)];
                float x00 = xc[-XS-1], x01 = xc[-XS], x02 = xc[-XS+1];
                float x10 = xc[-1],                   x12 = xc[1];
                float x20 = xc[XS-1],  x21 = xc[XS],  x22 = xc[XS+1];
                // cross-correlation (XLA conv does not flip kernels)
                float gfv = ((x20 + 2.f*x21 + x22) - (x00 + 2.f*x01 + x02)) * 0.125f;
                float gtv = ((x02 + 2.f*x12 + x22) - (x00 + 2.f*x10 + x20)) * 0.125f;
                float gte = gtv + EPSF;
                float g2f = gfv * gfv;
                float d2  = fmaf(gte, gte, g2f);
                float rh  = __builtin_amdgcn_rsqf(d2);
                ux = gte * rh;                  // cos(atan2(gf, gt+eps))
                uy = gfv * rh;                  // sin(atan2(gf, gt+eps))
                // m2 = |grad|^2 + eps = mag^2;  vx=mag*ux, vy=mag*uy =>
                // trp = vx^2+vy^2 = m2,  dfp = vx^2-vy^2 = m2(ux-uy)(ux+uy),
                // sxy = vx*vy = m2*ux*uy  (identical algebra, no sqrt needed)
                float m2 = fmaf(gtv, gtv, g2f) + EPSF;
                trp = m2;
                dfp = m2 * (ux - uy) * (ux + uy);
                sxy = m2 * ux * uy;
                tin = __builtin_amdgcn_rcpf(1.0f + fabsf(gtv));
                sf  = fabsf(gfv);
            }
            s_u[r * US + cc + 1] = pack_h2(ux, uy);   // +1 col shift
            if (r >= 1 && r < UROWS - 1 && cc >= 1 && cc < UROWS - 1) {
                int fi = (r - 1) * FS + (cc - 1);
                s_P0[fi] = pack_h2(trp, dfp);
                s_P1[fi] = pack_h2(sxy, tin);
                s_P2[fi] = pack_h2(sf, 0.f);   // .y = cv, filled in Phase C
            }
        }
        __syncthreads();

        // ---- Phase C: curv on 36x36, packed-h2 sobel over (ux,uy) ----
        for (int idx = tid; idx < FROWS * FROWS; idx += NTHR) {
            int r = idx / FROWS, cc = idx - r * FROWS;
            const __half2* up = &s_u[r * US + cc + 1];
            __half2 u00 = up[0],      u01 = up[1],      u02 = up[2];
            __half2 u10 = up[US],                       u12 = up[US+2];
            __half2 u20 = up[2*US],   u21 = up[2*US+1], u22 = up[2*US+2];
            // column sums (1,2,1 vertical) -> d/dx ; row sums -> d/dy, packed
            __half2 l0 = __hadd2(u00, u20); l0 = __hfma2(two, u10, l0);
            __half2 l2 = __hadd2(u02, u22); l2 = __hfma2(two, u12, l2);
            __half2 dxv = __hmul2(__hsub2(l2, l0), eighth);   // (dudx, dvdx)
            __half2 t0h = __hadd2(u00, u02); t0h = __hfma2(two, u01, t0h);
            __half2 t2h = __hadd2(u20, u22); t2h = __hfma2(two, u21, t2h);
            __half2 dyv = __hmul2(__hsub2(t2h, t0h), eighth); // (dudy, dvdy)
            float2 fx = __half22float2(dxv);
            float2 fy = __half22float2(dyv);
            float cv = __builtin_amdgcn_sqrtf(
                fmaf(fx.x, fx.x, fmaf(fx.y, fx.y,
                fmaf(fy.x, fy.x, fy.y * fy.y))) + EPSF);
            if (!FAST) {
                int gfr = f0 + r - 2, gtc = t0 + cc - 2;
                if (!(((unsigned)gfr < (unsigned)F_DIM) &
                      ((unsigned)gtc < (unsigned)T_DIM))) cv = 0.f;
            }
            ((__half*)s_P2)[2 * (r * FS + cc) + 1] = __float2half_rn(cv);
        }
        // D1 merged into this slot: j0 vertical (trace,diff): P0 -> tmp
        // (C touches s_u/s_P2.y; D1 touches s_P0/s_tmp — independent)
        vpass_pair(s_P0, (__half2*)s_tmp);
        __syncthreads();
    };

    for (int c = 0; c < C_DIM; ++c) {
        if (c) __syncthreads();   // protect LDS reuse (c==1 only)

        const float* xp = x_in + (size_t)(b * C_DIM + c) * F_DIM * T_DIM;
        if (interior) phaseABCD1(xp, BoolC<true>{});
        else          phaseABCD1(xp, BoolC<false>{});

        // ====== Phase D: separable jobs; job k horiz fused with job k+1 vert ======
        float trace_s[2], diff_s[2];
        __half2* tmp_h2 = (__half2*)s_tmp;

        // D2: j0 horizontal (f32 accumulate, entropy core) ; j1 vertical: P1 -> P0
        #pragma unroll
        for (int s = 0; s < 2; ++s) {
            int ry = ty + 16 * s;
            float a = 0.f, bv = 0.f;
            #pragma unroll
            for (int j = 0; j < 5; ++j) {
                float2 v = __half22float2(tmp_h2[ry * FS + tx + j]);
                a += w[j] * v.x; bv += w[j] * v.y;
            }
            trace_s[s] = a; diff_s[s] = bv;
        }
        vpass_pair(s_P1, s_P0);
        __syncthreads();

        // D3: j1 horizontal (vxy,tp) + entropy/temporal ; j2 vertical: P2 -> tmp
        #pragma unroll
        for (int s = 0; s < 2; ++s) {
            int ry = ty + 16 * s;
            __half2 a = h2z;
            #pragma unroll
            for (int j = 0; j < 5; ++j)
                a = __hfma2(wh2[j], s_P0[ry * FS + tx + j], a);
            float2 v = __half22float2(a);          // (vxy_s, tp)
            float trace = trace_s[s], diff = diff_s[s];
            float disc  = __builtin_amdgcn_sqrtf(
                              fmaxf(diff * diff + 4.f * v.x * v.x, 0.f) + EPSF);
            float l1 = fmaxf(0.5f * (trace + disc), EPSF);
            float l2 = fmaxf(0.5f * (trace - disc), EPSF);
            float inv = __builtin_amdgcn_rcpf(l1 + l2 + EPSF);
            float p1 = l1 * inv, p2 = l2 * inv;
            // v_log_f32 IS log2 — matches reference's ln(p)/ln(2)
            float ent = -(p1 * __builtin_amdgcn_logf(p1 + EPSF)
                        + p2 * __builtin_amdgcn_logf(p2 + EPSF));
            acc[0][s] += 0.5f * clamp01(ent);
            acc[4][s] += 0.5f * clamp01(v.y);
        }
        vpass_pair(s_P2, tmp_h2);
        __syncthreads();

        // D4: j2 horizontal (sp,cvs) ; j3 vertical: u -> P1 (paired uint2)
        #pragma unroll
        for (int s = 0; s < 2; ++s) {
            int ry = ty + 16 * s;
            __half2 a = h2z;
            #pragma unroll
            for (int j = 0; j < 5; ++j)
                a = __hfma2(wh2[j], tmp_h2[ry * FS + tx + j], a);
            float2 v = __half22float2(a);          // (sp, cvs)
            acc[5][s] += 0.5f * clamp01(v.x);
            acc[2][s] += 0.5f * v.y;
        }
        {
            // u(r+i+1, cc+1), cc = 2p,2p+1 -> word (r+i+1)*US + 2 + 2p: aligned
            const uint2* su2 = (const uint2*)s_u;
            uint2* dP1 = (uint2*)s_P1;
            for (int idx = tid; idx < TILE * FH2; idx += NTHR) {
                int r = idx / FH2, p = idx - r * FH2;
                const uint2* sp = su2 + (r + 1) * (US/2) + 1 + p;
                __half2 a0 = h2z, a1 = h2z;
                #pragma unroll
                for (int i = 0; i < 5; ++i) {
                    uint2 v = sp[i * (US/2)];
                    a0 = __hfma2(wh2[i], *(const __half2*)&v.x, a0);
                    a1 = __hfma2(wh2[i], *(const __half2*)&v.y, a1);
                }
                uint2 o; o.x = *(const unsigned*)&a0; o.y = *(const unsigned*)&a1;
                dP1[idx] = o;
            }
        }
        __syncthreads();

        // D5: j3 horizontal (alignment) ; j4 vertical: x^2 -> tmp (paired float2)
        #pragma unroll
        for (int s = 0; s < 2; ++s) {
            int ry = ty + 16 * s;
            __half2 a = h2z;
            #pragma unroll
            for (int j = 0; j < 5; ++j)
                a = __hfma2(wh2[j], s_P1[ry * FS + tx + j], a);
            float2 v = __half22float2(a);          // (ua, va)
            acc[1][s] += 0.5f * clamp01(
                __builtin_amdgcn_sqrtf(v.x * v.x + v.y * v.y + EPSF));
        }
        {
            // x(r+i+2, cc+2), cc = 2p,2p+1 -> word (r+i+2)*XS + 2 + 2p: aligned
            const float2* sx2 = (const float2*)s_x;
            float2* dt2 = (float2*)s_tmp;
            for (int idx = tid; idx < TILE * FH2; idx += NTHR) {
                int r = idx / FH2, p = idx - r * FH2;
                const float2* sp = sx2 + (r + 2) * (XS/2) + 1 + p;
                float a = 0.f, bv = 0.f;
                #pragma unroll
                for (int i = 0; i < 5; ++i) {
                    float2 v = sp[i * (XS/2)];
                    a  = fmaf(w[i], v.x * v.x, a);
                    bv = fmaf(w[i], v.y * v.y, bv);
                }
                dt2[idx] = make_float2(a, bv);
            }
        }
        __syncthreads();

        // D6: j4 horizontal (le) + harmonic epilogue (no trailing barrier)
        #pragma unroll
        for (int s = 0; s < 2; ++s) {
            int ry = ty + 16 * s;
            float le = 0.f;
            #pragma unroll
            for (int j = 0; j < 5; ++j)
                le += w[j] * s_tmp[ry * FS + tx + j];
            float xm  = s_x[(ry + 1) * XS + tx + 4];
            float x0v = s_x[(ry + 4) * XS + tx + 4];
            float xpv = s_x[(ry + 7) * XS + tx + 4];
            float harm = fabsf(2.f * x0v - xm - xpv);
            acc[3][s] += 0.5f * clamp01(harm * __builtin_amdgcn_rcpf(le + EPSF));
        }
    }

    // ---- write 6 output planes, coalesced ----
    const size_t plane = (size_t)B_DIM * F_DIM * T_DIM;
    const size_t base  = (size_t)b * F_DIM * T_DIM + (size_t)f0 * T_DIM + t0 + tx;
    #pragma unroll
    for (int k = 0; k < 6; ++k)
        #pragma unroll
        for (int s = 0; s < 2; ++s)
            out[k * plane + base + (size_t)(ty + 16 * s) * T_DIM] = acc[k][s];
}

extern "C" void kernel_launch(void* const* d_in, const int* in_sizes, int n_in,
                              void* d_out, int out_size, void* d_ws, size_t ws_size,
                              hipStream_t stream) {
    const float* x  = (const float*)d_in[0];
    const float* gk = (const float*)d_in[1];
    float* out = (float*)d_out;
    dim3 grid(T_DIM / TILE, F_DIM / TILE, B_DIM);   // 64 x 8 x 8 = 4096 blocks
    dim3 block(32, 16);                             // 512 threads = 8 waves
    audio_struct_fused<<<grid, block, 0, stream>>>(x, gk, out);
}

// Round 7
// 207.373 us; speedup vs baseline: 1.2849x; 1.2849x over previous
//
#include <hip/hip_runtime.h>
#include <hip/hip_fp16.h>

// AudioStructuralAnalyzer fused kernel, round 9.
// vs round 8 (170-245 us REGRESSION): __launch_bounds__(512, 8) squeezed the
// allocator to 32 VGPR -> massive scratch spills (FETCH 70->240 MB, WRITE
// 168->418 MB) and scratch-limited occupancy (6%). The "8" behaved ~2x
// tighter than waves-per-EU arithmetic (consistent with min-BLOCKS
// semantics: 8 blocks x 8 waves = 64 waves/CU -> 512/16 = 32 VGPR).
// ONE change: __launch_bounds__(512, 4) — under either semantics the
// allocator gets >=64 VGPR (the 256-thr build fit 64 with MORE state).
// LDS (32.6 KB) still caps at 4 blocks/CU x 8 waves = 32 waves/CU.
// This is the clean test of the occupancy hypothesis from round 7.
// Arithmetic bit-identical to rounds 4/7/8 (absmax stays 0.00390625).

#define F_DIM 256
#define T_DIM 2048
#define B_DIM 8
#define C_DIM 2
#define TILE  32
#define NTHR  512

#define XROWS 40          // x tile: halo 4
#define XS    40          // even stride (float2 loads stay aligned)
#define UROWS 38          // (ux,uy): halo 3
#define US    40          // stored with +1 col shift: u(r,cc) at word r*US+cc+1
#define FROWS 36          // field tiles: halo 2
#define FS    36
#define FH2   18          // FS/2 uint2 pairs per row
#define EPSF  1e-10f

template<bool V> struct BoolC { static constexpr bool value = V; };

static __device__ __forceinline__ __half2 pack_h2(float a, float b) {
    auto v = __builtin_amdgcn_cvt_pkrtz(a, b);   // v_cvt_pkrtz_f16_f32, 1 inst
    return *(__half2*)&v;
}
static __device__ __forceinline__ float clamp01(float x) {
    return fminf(fmaxf(x, 0.f), 1.f);
}

__global__ __launch_bounds__(512, 4)
void audio_struct_fused(const float* __restrict__ x_in,
                        const float* __restrict__ gk_in,
                        float* __restrict__ out)
{
    __shared__ __align__(16) float   s_x [XROWS*XS];    // 6400 B
    __shared__ __align__(16) __half2 s_u [UROWS*US];    // 6080 B (ux,uy), col-shifted
    __shared__ __align__(16) __half2 s_P0[FROWS*FS];    // 5184 B (trace,diff)
    __shared__ __align__(16) __half2 s_P1[FROWS*FS];    // 5184 B (sxy,tin) -> (ua,va)
    __shared__ __align__(16) __half2 s_P2[FROWS*FS];    // 5184 B (sf,cv)
    __shared__ __align__(16) float   s_tmp[TILE*FS];    // 4608 B ping-pong
    // total 32640 B -> 4 blocks/CU x 8 waves = 32 waves/CU cap

    const int tx  = threadIdx.x;          // 0..31 (time)
    const int ty  = threadIdx.y;          // 0..15 (freq)
    const int tid = ty * 32 + tx;         // 0..511
    const int t0  = blockIdx.x * TILE;
    const int f0  = blockIdx.y * TILE;
    const int b   = blockIdx.z;

    // 1D gaussian = normalized middle row of the separable 5x5 kernel
    float r0 = gk_in[10], r1 = gk_in[11], r2 = gk_in[12], r3 = gk_in[13], r4 = gk_in[14];
    float winv = __builtin_amdgcn_rcpf(r0 + r1 + r2 + r3 + r4);
    const float w[5] = {r0*winv, r1*winv, r2*winv, r3*winv, r4*winv};
    const __half2 wh2[5] = {pack_h2(w[0],w[0]), pack_h2(w[1],w[1]), pack_h2(w[2],w[2]),
                            pack_h2(w[3],w[3]), pack_h2(w[4],w[4])};
    const __half2 h2z    = pack_h2(0.f, 0.f);
    const __half2 two    = pack_h2(2.f, 2.f);
    const __half2 eighth = pack_h2(0.125f, 0.125f);

    // paired pk vertical pass: dst[idx] = sum_i w[i]*src[idx + i*FH2] (uint2 lanes)
    auto vpass_pair = [&](const __half2* src, __half2* dst) {
        const uint2* s = (const uint2*)src;
        uint2* d = (uint2*)dst;
        for (int idx = tid; idx < TILE * FH2; idx += NTHR) {
            __half2 a0 = h2z, a1 = h2z;
            #pragma unroll
            for (int i = 0; i < 5; ++i) {
                uint2 v = s[idx + i * FH2];
                a0 = __hfma2(wh2[i], *(const __half2*)&v.x, a0);
                a1 = __hfma2(wh2[i], *(const __half2*)&v.y, a1);
            }
            uint2 o; o.x = *(const unsigned*)&a0; o.y = *(const unsigned*)&a1;
            d[idx] = o;
        }
    };

    float acc[6][2];
    #pragma unroll
    for (int k = 0; k < 6; ++k)
        #pragma unroll
        for (int s = 0; s < 2; ++s) acc[k][s] = 0.0f;

    const bool interior = (f0 >= 4) && (f0 + TILE + 4 <= F_DIM) &&
                          (t0 >= 4) && (t0 + TILE + 4 <= T_DIM);

    // ---- Phases A, B, C(+D1) templated on interior fast path ----
    auto phaseABCD1 = [&](const float* xp, auto FASTC) {
        constexpr bool FAST = decltype(FASTC)::value;

        // ---- Phase A: load x tile + halo 4 (float2, never straddles edges) ----
        for (int idx = tid; idx < XROWS * 20; idx += NTHR) {
            int r  = idx / 20, c2 = idx - r * 20;
            float2 v;
            if (FAST) {
                v = *(const float2*)(xp + (size_t)(f0 + r - 4) * T_DIM + (t0 + c2 * 2 - 4));
            } else {
                int gf = f0 + r - 4;
                int gt = t0 + c2 * 2 - 4;
                v = make_float2(0.f, 0.f);
                if ((unsigned)gf < (unsigned)F_DIM && (unsigned)gt < (unsigned)T_DIM)
                    v = *(const float2*)(xp + (size_t)gf * T_DIM + gt);
            }
            *(float2*)&s_x[r * XS + c2 * 2] = v;
        }
        __syncthreads();

        // ---- Phase B: (ux,uy) on 38x38; packed fields on 36x36 ----
        for (int idx = tid; idx < UROWS * UROWS; idx += NTHR) {
            int r = idx / UROWS, cc = idx - r * UROWS;
            float ux = 0.f, uy = 0.f, trp = 0.f, dfp = 0.f, sxy = 0.f,
                  tin = 0.f, sf = 0.f;
            bool ok = true;
            if (!FAST) {
                int gfr = f0 + r - 3, gtc = t0 + cc - 3;
                ok = ((unsigned)gfr < (unsigned)F_DIM) & ((unsigned)gtc < (unsigned)T_DIM);
            }
            if (ok) {
                const float* xc = &s_x[(r + 1) * XS + (cc + 1)];
                float x00 = xc[-XS-1], x01 = xc[-XS], x02 = xc[-XS+1];
                float x10 = xc[-1],                   x12 = xc[1];
                float x20 = xc[XS-1],  x21 = xc[XS],  x22 = xc[XS+1];
                // cross-correlation (XLA conv does not flip kernels)
                float gfv = ((x20 + 2.f*x21 + x22) - (x00 + 2.f*x01 + x02)) * 0.125f;
                float gtv = ((x02 + 2.f*x12 + x22) - (x00 + 2.f*x10 + x20)) * 0.125f;
                float gte = gtv + EPSF;
                float g2f = gfv * gfv;
                float d2  = fmaf(gte, gte, g2f);
                float rh  = __builtin_amdgcn_rsqf(d2);
                ux = gte * rh;                  // cos(atan2(gf, gt+eps))
                uy = gfv * rh;                  // sin(atan2(gf, gt+eps))
                // m2 = |grad|^2 + eps = mag^2;  vx=mag*ux, vy=mag*uy =>
                // trp = vx^2+vy^2 = m2,  dfp = vx^2-vy^2 = m2(ux-uy)(ux+uy),
                // sxy = vx*vy = m2*ux*uy  (identical algebra, no sqrt needed)
                float m2 = fmaf(gtv, gtv, g2f) + EPSF;
                trp = m2;
                dfp = m2 * (ux - uy) * (ux + uy);
                sxy = m2 * ux * uy;
                tin = __builtin_amdgcn_rcpf(1.0f + fabsf(gtv));
                sf  = fabsf(gfv);
            }
            s_u[r * US + cc + 1] = pack_h2(ux, uy);   // +1 col shift
            if (r >= 1 && r < UROWS - 1 && cc >= 1 && cc < UROWS - 1) {
                int fi = (r - 1) * FS + (cc - 1);
                s_P0[fi] = pack_h2(trp, dfp);
                s_P1[fi] = pack_h2(sxy, tin);
                s_P2[fi] = pack_h2(sf, 0.f);   // .y = cv, filled in Phase C
            }
        }
        __syncthreads();

        // ---- Phase C: curv on 36x36, packed-h2 sobel over (ux,uy) ----
        for (int idx = tid; idx < FROWS * FROWS; idx += NTHR) {
            int r = idx / FROWS, cc = idx - r * FROWS;
            const __half2* up = &s_u[r * US + cc + 1];
            __half2 u00 = up[0],      u01 = up[1],      u02 = up[2];
            __half2 u10 = up[US],                       u12 = up[US+2];
            __half2 u20 = up[2*US],   u21 = up[2*US+1], u22 = up[2*US+2];
            // column sums (1,2,1 vertical) -> d/dx ; row sums -> d/dy, packed
            __half2 l0 = __hadd2(u00, u20); l0 = __hfma2(two, u10, l0);
            __half2 l2 = __hadd2(u02, u22); l2 = __hfma2(two, u12, l2);
            __half2 dxv = __hmul2(__hsub2(l2, l0), eighth);   // (dudx, dvdx)
            __half2 t0h = __hadd2(u00, u02); t0h = __hfma2(two, u01, t0h);
            __half2 t2h = __hadd2(u20, u22); t2h = __hfma2(two, u21, t2h);
            __half2 dyv = __hmul2(__hsub2(t2h, t0h), eighth); // (dudy, dvdy)
            float2 fx = __half22float2(dxv);
            float2 fy = __half22float2(dyv);
            float cv = __builtin_amdgcn_sqrtf(
                fmaf(fx.x, fx.x, fmaf(fx.y, fx.y,
                fmaf(fy.x, fy.x, fy.y * fy.y))) + EPSF);
            if (!FAST) {
                int gfr = f0 + r - 2, gtc = t0 + cc - 2;
                if (!(((unsigned)gfr < (unsigned)F_DIM) &
                      ((unsigned)gtc < (unsigned)T_DIM))) cv = 0.f;
            }
            ((__half*)s_P2)[2 * (r * FS + cc) + 1] = __float2half_rn(cv);
        }
        // D1 merged into this slot: j0 vertical (trace,diff): P0 -> tmp
        // (C touches s_u/s_P2.y; D1 touches s_P0/s_tmp — independent)
        vpass_pair(s_P0, (__half2*)s_tmp);
        __syncthreads();
    };

    for (int c = 0; c < C_DIM; ++c) {
        if (c) __syncthreads();   // protect LDS reuse (c==1 only)

        const float* xp = x_in + (size_t)(b * C_DIM + c) * F_DIM * T_DIM;
        if (interior) phaseABCD1(xp, BoolC<true>{});
        else          phaseABCD1(xp, BoolC<false>{});

        // ====== Phase D: separable jobs; job k horiz fused with job k+1 vert ======
        float trace_s[2], diff_s[2];
        __half2* tmp_h2 = (__half2*)s_tmp;

        // D2: j0 horizontal (f32 accumulate, entropy core) ; j1 vertical: P1 -> P0
        #pragma unroll
        for (int s = 0; s < 2; ++s) {
            int ry = ty + 16 * s;
            float a = 0.f, bv = 0.f;
            #pragma unroll
            for (int j = 0; j < 5; ++j) {
                float2 v = __half22float2(tmp_h2[ry * FS + tx + j]);
                a += w[j] * v.x; bv += w[j] * v.y;
            }
            trace_s[s] = a; diff_s[s] = bv;
        }
        vpass_pair(s_P1, s_P0);
        __syncthreads();

        // D3: j1 horizontal (vxy,tp) + entropy/temporal ; j2 vertical: P2 -> tmp
        #pragma unroll
        for (int s = 0; s < 2; ++s) {
            int ry = ty + 16 * s;
            __half2 a = h2z;
            #pragma unroll
            for (int j = 0; j < 5; ++j)
                a = __hfma2(wh2[j], s_P0[ry * FS + tx + j], a);
            float2 v = __half22float2(a);          // (vxy_s, tp)
            float trace = trace_s[s], diff = diff_s[s];
            float disc  = __builtin_amdgcn_sqrtf(
                              fmaxf(diff * diff + 4.f * v.x * v.x, 0.f) + EPSF);
            float l1 = fmaxf(0.5f * (trace + disc), EPSF);
            float l2 = fmaxf(0.5f * (trace - disc), EPSF);
            float inv = __builtin_amdgcn_rcpf(l1 + l2 + EPSF);
            float p1 = l1 * inv, p2 = l2 * inv;
            // v_log_f32 IS log2 — matches reference's ln(p)/ln(2)
            float ent = -(p1 * __builtin_amdgcn_logf(p1 + EPSF)
                        + p2 * __builtin_amdgcn_logf(p2 + EPSF));
            acc[0][s] += 0.5f * clamp01(ent);
            acc[4][s] += 0.5f * clamp01(v.y);
        }
        vpass_pair(s_P2, tmp_h2);
        __syncthreads();

        // D4: j2 horizontal (sp,cvs) ; j3 vertical: u -> P1 (paired uint2)
        #pragma unroll
        for (int s = 0; s < 2; ++s) {
            int ry = ty + 16 * s;
            __half2 a = h2z;
            #pragma unroll
            for (int j = 0; j < 5; ++j)
                a = __hfma2(wh2[j], tmp_h2[ry * FS + tx + j], a);
            float2 v = __half22float2(a);          // (sp, cvs)
            acc[5][s] += 0.5f * clamp01(v.x);
            acc[2][s] += 0.5f * v.y;
        }
        {
            // u(r+i+1, cc+1), cc = 2p,2p+1 -> word (r+i+1)*US + 2 + 2p: aligned
            const uint2* su2 = (const uint2*)s_u;
            uint2* dP1 = (uint2*)s_P1;
            for (int idx = tid; idx < TILE * FH2; idx += NTHR) {
                int r = idx / FH2, p = idx - r * FH2;
                const uint2* sp = su2 + (r + 1) * (US/2) + 1 + p;
                __half2 a0 = h2z, a1 = h2z;
                #pragma unroll
                for (int i = 0; i < 5; ++i) {
                    uint2 v = sp[i * (US/2)];
                    a0 = __hfma2(wh2[i], *(const __half2*)&v.x, a0);
                    a1 = __hfma2(wh2[i], *(const __half2*)&v.y, a1);
                }
                uint2 o; o.x = *(const unsigned*)&a0; o.y = *(const unsigned*)&a1;
                dP1[idx] = o;
            }
        }
        __syncthreads();

        // D5: j3 horizontal (alignment) ; j4 vertical: x^2 -> tmp (paired float2)
        #pragma unroll
        for (int s = 0; s < 2; ++s) {
            int ry = ty + 16 * s;
            __half2 a = h2z;
            #pragma unroll
            for (int j = 0; j < 5; ++j)
                a = __hfma2(wh2[j], s_P1[ry * FS + tx + j], a);
            float2 v = __half22float2(a);          // (ua, va)
            acc[1][s] += 0.5f * clamp01(
                __builtin_amdgcn_sqrtf(v.x * v.x + v.y * v.y + EPSF));
        }
        {
            // x(r+i+2, cc+2), cc = 2p,2p+1 -> word (r+i+2)*XS + 2 + 2p: aligned
            const float2* sx2 = (const float2*)s_x;
            float2* dt2 = (float2*)s_tmp;
            for (int idx = tid; idx < TILE * FH2; idx += NTHR) {
                int r = idx / FH2, p = idx - r * FH2;
                const float2* sp = sx2 + (r + 2) * (XS/2) + 1 + p;
                float a = 0.f, bv = 0.f;
                #pragma unroll
                for (int i = 0; i < 5; ++i) {
                    float2 v = sp[i * (XS/2)];
                    a  = fmaf(w[i], v.x * v.x, a);
                    bv = fmaf(w[i], v.y * v.y, bv);
                }
                dt2[idx] = make_float2(a, bv);
            }
        }
        __syncthreads();

        // D6: j4 horizontal (le) + harmonic epilogue (no trailing barrier)
        #pragma unroll
        for (int s = 0; s < 2; ++s) {
            int ry = ty + 16 * s;
            float le = 0.f;
            #pragma unroll
            for (int j = 0; j < 5; ++j)
                le += w[j] * s_tmp[ry * FS + tx + j];
            float xm  = s_x[(ry + 1) * XS + tx + 4];
            float x0v = s_x[(ry + 4) * XS + tx + 4];
            float xpv = s_x[(ry + 7) * XS + tx + 4];
            float harm = fabsf(2.f * x0v - xm - xpv);
            acc[3][s] += 0.5f * clamp01(harm * __builtin_amdgcn_rcpf(le + EPSF));
        }
    }

    // ---- write 6 output planes, coalesced ----
    const size_t plane = (size_t)B_DIM * F_DIM * T_DIM;
    const size_t base  = (size_t)b * F_DIM * T_DIM + (size_t)f0 * T_DIM + t0 + tx;
    #pragma unroll
    for (int k = 0; k < 6; ++k)
        #pragma unroll
        for (int s = 0; s < 2; ++s)
            out[k * plane + base + (size_t)(ty + 16 * s) * T_DIM] = acc[k][s];
}

extern "C" void kernel_launch(void* const* d_in, const int* in_sizes, int n_in,
                              void* d_out, int out_size, void* d_ws, size_t ws_size,
                              hipStream_t stream) {
    const float* x  = (const float*)d_in[0];
    const float* gk = (const float*)d_in[1];
    float* out = (float*)d_out;
    dim3 grid(T_DIM / TILE, F_DIM / TILE, B_DIM);   // 64 x 8 x 8 = 4096 blocks
    dim3 block(32, 16);                             // 512 threads = 8 waves
    audio_struct_fused<<<grid, block, 0, stream>>>(x, gk, out);
}

// Round 8
// 205.601 us; speedup vs baseline: 1.2960x; 1.0086x over previous
//
#include <hip/hip_runtime.h>
#include <hip/hip_fp16.h>

// AudioStructuralAnalyzer fused kernel, round 10.
// vs round 9 (113 us dispatch, VALUBusy 56%, WRITE exactly ideal, spills gone):
//  - Dataflow re-plumb: new 5.2 KB s_P3 buffer breaks false dependences so the
//    five separable jobs fit in 3 fat slots instead of 6 thin ones:
//      CD1:  C  + v(P0->tmp) + v(P1->P3)
//      D23:  D2h(tmp)+D3h(P3)+entropy + v(P2->P0) + v(u->P1)
//      D45:  D4h(P0)+D5h(P1) + v(x^2->tmp)
//      D6:   unchanged
//    11 barriers/block (was 15); per-slot work ~2x -> better LDS-latency
//    hiding at the same occupancy.
//  - LDS 37824 B -> still 4 blocks/CU. Same 512-thr shape, launch_bounds(512,4)
//    (VGPR 48, no spills — proven in round 9).
// Arithmetic bit-identical to round 9 (absmax stays 0.00390625).

#define F_DIM 256
#define T_DIM 2048
#define B_DIM 8
#define C_DIM 2
#define TILE  32
#define NTHR  512

#define XROWS 40          // x tile: halo 4
#define XS    40          // even stride (float2 loads stay aligned)
#define UROWS 38          // (ux,uy): halo 3
#define US    40          // stored with +1 col shift: u(r,cc) at word r*US+cc+1
#define FROWS 36          // field tiles: halo 2
#define FS    36
#define FH2   18          // FS/2 uint2 pairs per row
#define EPSF  1e-10f

template<bool V> struct BoolC { static constexpr bool value = V; };

static __device__ __forceinline__ __half2 pack_h2(float a, float b) {
    auto v = __builtin_amdgcn_cvt_pkrtz(a, b);   // v_cvt_pkrtz_f16_f32, 1 inst
    return *(__half2*)&v;
}
static __device__ __forceinline__ float clamp01(float x) {
    return fminf(fmaxf(x, 0.f), 1.f);
}

__global__ __launch_bounds__(512, 4)
void audio_struct_fused(const float* __restrict__ x_in,
                        const float* __restrict__ gk_in,
                        float* __restrict__ out)
{
    __shared__ __align__(16) float   s_x [XROWS*XS];    // 6400 B
    __shared__ __align__(16) __half2 s_u [UROWS*US];    // 6080 B (ux,uy), col-shifted
    __shared__ __align__(16) __half2 s_P0[FROWS*FS];    // 5184 B (trace,diff) -> (sf,cv)v
    __shared__ __align__(16) __half2 s_P1[FROWS*FS];    // 5184 B (sxy,tin) -> (ux,uy)v
    __shared__ __align__(16) __half2 s_P2[FROWS*FS];    // 5184 B (sf,cv)
    __shared__ __align__(16) __half2 s_P3[FROWS*FS];    // 5184 B (sxy,tin)v
    __shared__ __align__(16) float   s_tmp[TILE*FS];    // 4608 B (trace,diff)v -> x^2 v
    // total 37824 B -> 4 blocks/CU x 8 waves = 32 waves/CU cap

    const int tx  = threadIdx.x;          // 0..31 (time)
    const int ty  = threadIdx.y;          // 0..15 (freq)
    const int tid = ty * 32 + tx;         // 0..511
    const int t0  = blockIdx.x * TILE;
    const int f0  = blockIdx.y * TILE;
    const int b   = blockIdx.z;

    // 1D gaussian = normalized middle row of the separable 5x5 kernel
    float r0 = gk_in[10], r1 = gk_in[11], r2 = gk_in[12], r3 = gk_in[13], r4 = gk_in[14];
    float winv = __builtin_amdgcn_rcpf(r0 + r1 + r2 + r3 + r4);
    const float w[5] = {r0*winv, r1*winv, r2*winv, r3*winv, r4*winv};
    const __half2 wh2[5] = {pack_h2(w[0],w[0]), pack_h2(w[1],w[1]), pack_h2(w[2],w[2]),
                            pack_h2(w[3],w[3]), pack_h2(w[4],w[4])};
    const __half2 h2z    = pack_h2(0.f, 0.f);
    const __half2 two    = pack_h2(2.f, 2.f);
    const __half2 eighth = pack_h2(0.125f, 0.125f);

    // paired pk vertical pass: dst[idx] = sum_i w[i]*src[idx + i*FH2] (uint2 lanes)
    auto vpass_pair = [&](const __half2* src, __half2* dst) {
        const uint2* s = (const uint2*)src;
        uint2* d = (uint2*)dst;
        for (int idx = tid; idx < TILE * FH2; idx += NTHR) {
            __half2 a0 = h2z, a1 = h2z;
            #pragma unroll
            for (int i = 0; i < 5; ++i) {
                uint2 v = s[idx + i * FH2];
                a0 = __hfma2(wh2[i], *(const __half2*)&v.x, a0);
                a1 = __hfma2(wh2[i], *(const __half2*)&v.y, a1);
            }
            uint2 o; o.x = *(const unsigned*)&a0; o.y = *(const unsigned*)&a1;
            d[idx] = o;
        }
    };

    float acc[6][2];
    #pragma unroll
    for (int k = 0; k < 6; ++k)
        #pragma unroll
        for (int s = 0; s < 2; ++s) acc[k][s] = 0.0f;

    const bool interior = (f0 >= 4) && (f0 + TILE + 4 <= F_DIM) &&
                          (t0 >= 4) && (t0 + TILE + 4 <= T_DIM);

    // ---- Phases A, B, CD1 templated on interior fast path ----
    auto phaseABC = [&](const float* xp, auto FASTC) {
        constexpr bool FAST = decltype(FASTC)::value;

        // ---- Phase A: load x tile + halo 4 (float2, never straddles edges) ----
        for (int idx = tid; idx < XROWS * 20; idx += NTHR) {
            int r  = idx / 20, c2 = idx - r * 20;
            float2 v;
            if (FAST) {
                v = *(const float2*)(xp + (size_t)(f0 + r - 4) * T_DIM + (t0 + c2 * 2 - 4));
            } else {
                int gf = f0 + r - 4;
                int gt = t0 + c2 * 2 - 4;
                v = make_float2(0.f, 0.f);
                if ((unsigned)gf < (unsigned)F_DIM && (unsigned)gt < (unsigned)T_DIM)
                    v = *(const float2*)(xp + (size_t)gf * T_DIM + gt);
            }
            *(float2*)&s_x[r * XS + c2 * 2] = v;
        }
        __syncthreads();

        // ---- Phase B: (ux,uy) on 38x38; packed fields on 36x36 ----
        for (int idx = tid; idx < UROWS * UROWS; idx += NTHR) {
            int r = idx / UROWS, cc = idx - r * UROWS;
            float ux = 0.f, uy = 0.f, trp = 0.f, dfp = 0.f, sxy = 0.f,
                  tin = 0.f, sf = 0.f;
            bool ok = true;
            if (!FAST) {
                int gfr = f0 + r - 3, gtc = t0 + cc - 3;
                ok = ((unsigned)gfr < (unsigned)F_DIM) & ((unsigned)gtc < (unsigned)T_DIM);
            }
            if (ok) {
                const float* xc = &s_x[(r + 1) * XS + (cc + 1)];
                float x00 = xc[-XS-1], x01 = xc[-XS], x02 = xc[-XS+1];
                float x10 = xc[-1],                   x12 = xc[1];
                float x20 = xc[XS-1],  x21 = xc[XS],  x22 = xc[XS+1];
                // cross-correlation (XLA conv does not flip kernels)
                float gfv = ((x20 + 2.f*x21 + x22) - (x00 + 2.f*x01 + x02)) * 0.125f;
                float gtv = ((x02 + 2.f*x12 + x22) - (x00 + 2.f*x10 + x20)) * 0.125f;
                float gte = gtv + EPSF;
                float g2f = gfv * gfv;
                float d2  = fmaf(gte, gte, g2f);
                float rh  = __builtin_amdgcn_rsqf(d2);
                ux = gte * rh;                  // cos(atan2(gf, gt+eps))
                uy = gfv * rh;                  // sin(atan2(gf, gt+eps))
                // m2 = |grad|^2 + eps = mag^2;  vx=mag*ux, vy=mag*uy =>
                // trp = vx^2+vy^2 = m2,  dfp = vx^2-vy^2 = m2(ux-uy)(ux+uy),
                // sxy = vx*vy = m2*ux*uy  (identical algebra, no sqrt needed)
                float m2 = fmaf(gtv, gtv, g2f) + EPSF;
                trp = m2;
                dfp = m2 * (ux - uy) * (ux + uy);
                sxy = m2 * ux * uy;
                tin = __builtin_amdgcn_rcpf(1.0f + fabsf(gtv));
                sf  = fabsf(gfv);
            }
            s_u[r * US + cc + 1] = pack_h2(ux, uy);   // +1 col shift
            if (r >= 1 && r < UROWS - 1 && cc >= 1 && cc < UROWS - 1) {
                int fi = (r - 1) * FS + (cc - 1);
                s_P0[fi] = pack_h2(trp, dfp);
                s_P1[fi] = pack_h2(sxy, tin);
                s_P2[fi] = pack_h2(sf, 0.f);   // .y = cv, filled in Phase C
            }
        }
        __syncthreads();

        // ---- Slot CD1: Phase C (u sobel -> P2.y) + v(P0->tmp) + v(P1->P3) ----
        for (int idx = tid; idx < FROWS * FROWS; idx += NTHR) {
            int r = idx / FROWS, cc = idx - r * FROWS;
            const __half2* up = &s_u[r * US + cc + 1];
            __half2 u00 = up[0],      u01 = up[1],      u02 = up[2];
            __half2 u10 = up[US],                       u12 = up[US+2];
            __half2 u20 = up[2*US],   u21 = up[2*US+1], u22 = up[2*US+2];
            // column sums (1,2,1 vertical) -> d/dx ; row sums -> d/dy, packed
            __half2 l0 = __hadd2(u00, u20); l0 = __hfma2(two, u10, l0);
            __half2 l2 = __hadd2(u02, u22); l2 = __hfma2(two, u12, l2);
            __half2 dxv = __hmul2(__hsub2(l2, l0), eighth);   // (dudx, dvdx)
            __half2 t0h = __hadd2(u00, u02); t0h = __hfma2(two, u01, t0h);
            __half2 t2h = __hadd2(u20, u22); t2h = __hfma2(two, u21, t2h);
            __half2 dyv = __hmul2(__hsub2(t2h, t0h), eighth); // (dudy, dvdy)
            float2 fx = __half22float2(dxv);
            float2 fy = __half22float2(dyv);
            float cv = __builtin_amdgcn_sqrtf(
                fmaf(fx.x, fx.x, fmaf(fx.y, fx.y,
                fmaf(fy.x, fy.x, fy.y * fy.y))) + EPSF);
            if (!FAST) {
                int gfr = f0 + r - 2, gtc = t0 + cc - 2;
                if (!(((unsigned)gfr < (unsigned)F_DIM) &
                      ((unsigned)gtc < (unsigned)T_DIM))) cv = 0.f;
            }
            ((__half*)s_P2)[2 * (r * FS + cc) + 1] = __float2half_rn(cv);
        }
        vpass_pair(s_P0, (__half2*)s_tmp);   // j0 vertical: (trace,diff)
        vpass_pair(s_P1, s_P3);              // j1 vertical: (sxy,tin)
        __syncthreads();
    };

    for (int c = 0; c < C_DIM; ++c) {
        if (c) __syncthreads();   // protect LDS reuse (c==1 only)

        const float* xp = x_in + (size_t)(b * C_DIM + c) * F_DIM * T_DIM;
        if (interior) phaseABC(xp, BoolC<true>{});
        else          phaseABC(xp, BoolC<false>{});

        __half2* tmp_h2 = (__half2*)s_tmp;

        // ====== Slot D23: j0h + j1h + entropy/temporal ; v(P2->P0) ; v(u->P1) ======
        {
            float trace_s[2], diff_s[2];
            #pragma unroll
            for (int s = 0; s < 2; ++s) {
                int ry = ty + 16 * s;
                float a = 0.f, bv = 0.f;
                #pragma unroll
                for (int j = 0; j < 5; ++j) {
                    float2 v = __half22float2(tmp_h2[ry * FS + tx + j]);
                    a += w[j] * v.x; bv += w[j] * v.y;
                }
                trace_s[s] = a; diff_s[s] = bv;
            }
            #pragma unroll
            for (int s = 0; s < 2; ++s) {
                int ry = ty + 16 * s;
                __half2 a = h2z;
                #pragma unroll
                for (int j = 0; j < 5; ++j)
                    a = __hfma2(wh2[j], s_P3[ry * FS + tx + j], a);
                float2 v = __half22float2(a);          // (vxy_s, tp)
                float trace = trace_s[s], diff = diff_s[s];
                float disc  = __builtin_amdgcn_sqrtf(
                                  fmaxf(diff * diff + 4.f * v.x * v.x, 0.f) + EPSF);
                float l1 = fmaxf(0.5f * (trace + disc), EPSF);
                float l2 = fmaxf(0.5f * (trace - disc), EPSF);
                float inv = __builtin_amdgcn_rcpf(l1 + l2 + EPSF);
                float p1 = l1 * inv, p2 = l2 * inv;
                // v_log_f32 IS log2 — matches reference's ln(p)/ln(2)
                float ent = -(p1 * __builtin_amdgcn_logf(p1 + EPSF)
                            + p2 * __builtin_amdgcn_logf(p2 + EPSF));
                acc[0][s] += 0.5f * clamp01(ent);
                acc[4][s] += 0.5f * clamp01(v.y);
            }
            vpass_pair(s_P2, s_P0);          // j2 vertical: (sf,cv) -> P0
            {
                // j3 vertical: u -> P1.  u(r+i+1, cc+1), cc = 2p,2p+1
                // -> word (r+i+1)*US + 2 + 2p: uint2-aligned
                const uint2* su2 = (const uint2*)s_u;
                uint2* dP1 = (uint2*)s_P1;
                for (int idx = tid; idx < TILE * FH2; idx += NTHR) {
                    int r = idx / FH2, p = idx - r * FH2;
                    const uint2* sp = su2 + (r + 1) * (US/2) + 1 + p;
                    __half2 a0 = h2z, a1 = h2z;
                    #pragma unroll
                    for (int i = 0; i < 5; ++i) {
                        uint2 v = sp[i * (US/2)];
                        a0 = __hfma2(wh2[i], *(const __half2*)&v.x, a0);
                        a1 = __hfma2(wh2[i], *(const __half2*)&v.y, a1);
                    }
                    uint2 o; o.x = *(const unsigned*)&a0; o.y = *(const unsigned*)&a1;
                    dP1[idx] = o;
                }
            }
        }
        __syncthreads();

        // ====== Slot D45: j2h (P0) + j3h (P1) ; v(x^2 -> tmp) ======
        #pragma unroll
        for (int s = 0; s < 2; ++s) {
            int ry = ty + 16 * s;
            __half2 a = h2z;
            #pragma unroll
            for (int j = 0; j < 5; ++j)
                a = __hfma2(wh2[j], s_P0[ry * FS + tx + j], a);
            float2 v = __half22float2(a);          // (sp, cvs)
            acc[5][s] += 0.5f * clamp01(v.x);
            acc[2][s] += 0.5f * v.y;
        }
        #pragma unroll
        for (int s = 0; s < 2; ++s) {
            int ry = ty + 16 * s;
            __half2 a = h2z;
            #pragma unroll
            for (int j = 0; j < 5; ++j)
                a = __hfma2(wh2[j], s_P1[ry * FS + tx + j], a);
            float2 v = __half22float2(a);          // (ua, va)
            acc[1][s] += 0.5f * clamp01(
                __builtin_amdgcn_sqrtf(v.x * v.x + v.y * v.y + EPSF));
        }
        {
            // j4 vertical: x(r+i+2, cc+2), cc = 2p,2p+1
            // -> word (r+i+2)*XS + 2 + 2p: float2-aligned
            const float2* sx2 = (const float2*)s_x;
            float2* dt2 = (float2*)s_tmp;
            for (int idx = tid; idx < TILE * FH2; idx += NTHR) {
                int r = idx / FH2, p = idx - r * FH2;
                const float2* sp = sx2 + (r + 2) * (XS/2) + 1 + p;
                float a = 0.f, bv = 0.f;
                #pragma unroll
                for (int i = 0; i < 5; ++i) {
                    float2 v = sp[i * (XS/2)];
                    a  = fmaf(w[i], v.x * v.x, a);
                    bv = fmaf(w[i], v.y * v.y, bv);
                }
                dt2[idx] = make_float2(a, bv);
            }
        }
        __syncthreads();

        // ====== Slot D6: j4h (le) + harmonic epilogue (no trailing barrier) ======
        #pragma unroll
        for (int s = 0; s < 2; ++s) {
            int ry = ty + 16 * s;
            float le = 0.f;
            #pragma unroll
            for (int j = 0; j < 5; ++j)
                le += w[j] * s_tmp[ry * FS + tx + j];
            float xm  = s_x[(ry + 1) * XS + tx + 4];
            float x0v = s_x[(ry + 4) * XS + tx + 4];
            float xpv = s_x[(ry + 7) * XS + tx + 4];
            float harm = fabsf(2.f * x0v - xm - xpv);
            acc[3][s] += 0.5f * clamp01(harm * __builtin_amdgcn_rcpf(le + EPSF));
        }
    }

    // ---- write 6 output planes, coalesced ----
    const size_t plane = (size_t)B_DIM * F_DIM * T_DIM;
    const size_t base  = (size_t)b * F_DIM * T_DIM + (size_t)f0 * T_DIM + t0 + tx;
    #pragma unroll
    for (int k = 0; k < 6; ++k)
        #pragma unroll
        for (int s = 0; s < 2; ++s)
            out[k * plane + base + (size_t)(ty + 16 * s) * T_DIM] = acc[k][s];
}

extern "C" void kernel_launch(void* const* d_in, const int* in_sizes, int n_in,
                              void* d_out, int out_size, void* d_ws, size_t ws_size,
                              hipStream_t stream) {
    const float* x  = (const float*)d_in[0];
    const float* gk = (const float*)d_in[1];
    float* out = (float*)d_out;
    dim3 grid(T_DIM / TILE, F_DIM / TILE, B_DIM);   // 64 x 8 x 8 = 4096 blocks
    dim3 block(32, 16);                             // 512 threads = 8 waves
    audio_struct_fused<<<grid, block, 0, stream>>>(x, gk, out);
}